// Round 1
// baseline (455.429 us; speedup 1.0000x reference)
//
#include <hip/hip_runtime.h>
#include <stdint.h>

typedef unsigned short u16;
typedef __attribute__((ext_vector_type(4))) unsigned short u16x4;
typedef __attribute__((ext_vector_type(4))) float f32x4;
typedef __attribute__((ext_vector_type(8))) __bf16 bf16x8;

#define M_DIM 16384
#define N_DIM 2048
#define K_DIM 2048
#define NELEM (M_DIM * K_DIM)      // 33554432
#define NGROUPS (NELEM / 4)        // 8388608
#define WELEM (N_DIM * K_DIM)      // 4194304

__device__ __forceinline__ u16 f2bf(float f) {
    union { float f; uint32_t u; } c; c.f = f;
    uint32_t r = c.u + 0x7FFFu + ((c.u >> 16) & 1u);   // round-to-nearest-even
    return (u16)(r >> 16);
}

// -------------------------------------------------------------------------
// Kernel 1: 2:4 prune + bf16 convert + global sum/sumsq reduction
// -------------------------------------------------------------------------
__global__ __launch_bounds__(256) void prune_kernel(const float* __restrict__ x,
                                                    u16* __restrict__ xsp,
                                                    float* __restrict__ sums) {
    float sx = 0.f, sxx = 0.f, sp = 0.f, spp = 0.f;
    const int stride = gridDim.x * 256;
    for (int g = blockIdx.x * 256 + threadIdx.x; g < NGROUPS; g += stride) {
        float4 v = ((const float4*)x)[g];
        float a0 = v.x, a1 = v.y, a2 = v.z, a3 = v.w;
        float b0 = fabsf(a0), b1 = fabsf(a1), b2 = fabsf(a2), b3 = fabsf(a3);
        // rank_i = #{j : |a_j|>|a_i|  or (|a_j|==|a_i| and j<i)} -> keep if rank<2
        // matches jax.lax.top_k tie-breaking (lower index wins)
        int r0 = (b1 > b0) + (b2 > b0) + (b3 > b0);
        int r1 = (b0 >= b1) + (b2 > b1) + (b3 > b1);
        int r2 = (b0 >= b2) + (b1 >= b2) + (b3 > b2);
        int r3 = (b0 >= b3) + (b1 >= b3) + (b2 >= b3);
        float k0 = (r0 < 2) ? a0 : 0.f;
        float k1 = (r1 < 2) ? a1 : 0.f;
        float k2 = (r2 < 2) ? a2 : 0.f;
        float k3 = (r3 < 2) ? a3 : 0.f;
        sx  += a0 + a1 + a2 + a3;
        sxx += a0*a0 + a1*a1 + a2*a2 + a3*a3;
        sp  += k0 + k1 + k2 + k3;
        spp += k0*k0 + k1*k1 + k2*k2 + k3*k3;
        u16x4 o;
        o.x = f2bf(k0); o.y = f2bf(k1); o.z = f2bf(k2); o.w = f2bf(k3);
        ((u16x4*)xsp)[g] = o;
    }
    // wave reduce (64 lanes)
    for (int off = 32; off > 0; off >>= 1) {
        sx  += __shfl_down(sx,  off, 64);
        sxx += __shfl_down(sxx, off, 64);
        sp  += __shfl_down(sp,  off, 64);
        spp += __shfl_down(spp, off, 64);
    }
    __shared__ float red[4][4];
    int wid = threadIdx.x >> 6, lane = threadIdx.x & 63;
    if (lane == 0) { red[wid][0] = sx; red[wid][1] = sxx; red[wid][2] = sp; red[wid][3] = spp; }
    __syncthreads();
    if (threadIdx.x < 4) {
        float t = red[0][threadIdx.x] + red[1][threadIdx.x] +
                  red[2][threadIdx.x] + red[3][threadIdx.x];
        atomicAdd(&sums[threadIdx.x], t);
    }
}

// -------------------------------------------------------------------------
// Kernel 2: weight fp32 -> bf16
// -------------------------------------------------------------------------
__global__ __launch_bounds__(256) void wconv_kernel(const float* __restrict__ w,
                                                    u16* __restrict__ wb) {
    int i = blockIdx.x * 256 + threadIdx.x;   // over WELEM/4 exactly
    float4 v = ((const float4*)w)[i];
    u16x4 o;
    o.x = f2bf(v.x); o.y = f2bf(v.y); o.z = f2bf(v.z); o.w = f2bf(v.w);
    ((u16x4*)wb)[i] = o;
}

// -------------------------------------------------------------------------
// Kernel 3: bf16 MFMA GEMM, m97 structure: 128x128 tile, BK=32,
// 4 waves x (4x4) mfma_f32_16x16x32_bf16, global_load_lds width=16.
// A = x_sp [M][K] bf16, B = W [N][K] bf16 (both K-contiguous), out fp32 [M][N].
// Epilogue scales by v = sqrt(var(x)/max(var(x_sp),1e-9)) from the 4 sums.
// -------------------------------------------------------------------------
#define GLD16(g, l) \
    __builtin_amdgcn_global_load_lds((__attribute__((address_space(1))) void*)(g), \
                                     (__attribute__((address_space(3))) void*)(l), 16, 0, 0)

__global__ __launch_bounds__(256) void gemm_kernel(const u16* __restrict__ A,
                                                   const u16* __restrict__ B,
                                                   const float* __restrict__ sums,
                                                   float* __restrict__ out) {
    __shared__ __align__(16) u16 As[128 * 32];   // 8 KiB, lane-linear (no pad: global_load_lds)
    __shared__ __align__(16) u16 Bs[128 * 32];   // 8 KiB

    const int tid  = threadIdx.x;
    const int lane = tid & 63;
    const int wid  = tid >> 6;
    const int wm   = (wid >> 1) * 64;   // wave tile origin in M within block
    const int wn   = (wid & 1) * 64;    // wave tile origin in N within block
    const int l15  = lane & 15;
    const int quad = lane >> 4;
    const int m0 = blockIdx.y * 128;
    const int n0 = blockIdx.x * 128;

    // staging: 128 rows x 32 k = 4096 elems = 512 x 8-elem (16B) chunks;
    // 256 threads x 2 rounds, LDS offset = chunk_idx*16B (lane-linear per wave)
    const int idx0 = tid;
    const int idx1 = tid + 256;
    const int rA0 = idx0 >> 2, sA0 = (idx0 & 3) * 8;
    const int rA1 = idx1 >> 2, sA1 = (idx1 & 3) * 8;
    const u16* gA0 = A + (size_t)(m0 + rA0) * K_DIM + sA0;
    const u16* gA1 = A + (size_t)(m0 + rA1) * K_DIM + sA1;
    const u16* gB0 = B + (size_t)(n0 + rA0) * K_DIM + sA0;
    const u16* gB1 = B + (size_t)(n0 + rA1) * K_DIM + sA1;

    f32x4 acc[4][4] = {};

    for (int kt = 0; kt < K_DIM / 32; ++kt) {
        GLD16(gA0, &As[idx0 * 8]);
        GLD16(gA1, &As[idx1 * 8]);
        GLD16(gB0, &Bs[idx0 * 8]);
        GLD16(gB1, &Bs[idx1 * 8]);
        gA0 += 32; gA1 += 32; gB0 += 32; gB1 += 32;
        __syncthreads();   // drains vmcnt (global_load_lds) + lgkmcnt

        const bf16x8* Ap = (const bf16x8*)As;
        const bf16x8* Bp = (const bf16x8*)Bs;
        bf16x8 aF[4], bF[4];
#pragma unroll
        for (int i = 0; i < 4; ++i)
            aF[i] = Ap[(wm + i * 16 + l15) * 4 + quad];   // A[m=l15][k=quad*8+j]
#pragma unroll
        for (int j = 0; j < 4; ++j)
            bF[j] = Bp[(wn + j * 16 + l15) * 4 + quad];   // B[n=l15][k=quad*8+j]
#pragma unroll
        for (int i = 0; i < 4; ++i)
#pragma unroll
            for (int j = 0; j < 4; ++j)
                acc[i][j] = __builtin_amdgcn_mfma_f32_16x16x32_bf16(aF[i], bF[j], acc[i][j], 0, 0, 0);
        __syncthreads();   // protect LDS from next iter's staging
    }

    // v = sqrt(var(x,ddof=1) / max(var(x_sp,ddof=1), 1e-9))
    const float n   = (float)NELEM;
    const float sx  = sums[0], sxx = sums[1], sp = sums[2], spp = sums[3];
    float varx = (sxx - sx * sx / n) / (n - 1.f);
    float varp = (spp - sp * sp / n) / (n - 1.f);
    varp = fmaxf(varp, 1e-9f);
    const float v = sqrtf(varx / varp);

    // C/D layout: col = lane&15, row = quad*4 + reg
    float* op = out + (size_t)(m0 + wm) * N_DIM + n0 + wn;
#pragma unroll
    for (int i = 0; i < 4; ++i)
#pragma unroll
        for (int j = 0; j < 4; ++j)
#pragma unroll
            for (int r = 0; r < 4; ++r)
                op[(size_t)(i * 16 + quad * 4 + r) * N_DIM + j * 16 + l15] = acc[i][j][r] * v;
}

extern "C" void kernel_launch(void* const* d_in, const int* in_sizes, int n_in,
                              void* d_out, int out_size, void* d_ws, size_t ws_size,
                              hipStream_t stream) {
    const float* x = (const float*)d_in[0];
    const float* w = (const float*)d_in[1];
    float* out = (float*)d_out;

    u16* xsp   = (u16*)d_ws;                 // 64 MiB: bf16 x_sp [16384][2048]
    u16* wb    = xsp + NELEM;                // 8 MiB:  bf16 W    [2048][2048]
    float* sums = (float*)(wb + WELEM);      // 16 B:   {sum_x, sumsq_x, sum_sp, sumsq_sp}

    hipMemsetAsync(sums, 0, 4 * sizeof(float), stream);
    prune_kernel<<<8192, 256, 0, stream>>>(x, xsp, sums);
    wconv_kernel<<<WELEM / 4 / 256, 256, 0, stream>>>(w, wb);
    dim3 grid(N_DIM / 128, M_DIM / 128);
    gemm_kernel<<<grid, 256, 0, stream>>>(xsp, wb, sums, out);
}

// Round 2
// 400.425 us; speedup vs baseline: 1.1374x; 1.1374x over previous
//
#include <hip/hip_runtime.h>
#include <stdint.h>

typedef unsigned short u16;
typedef __attribute__((ext_vector_type(4))) unsigned short u16x4;
typedef __attribute__((ext_vector_type(4))) float f32x4;
typedef __attribute__((ext_vector_type(8))) __bf16 bf16x8;

#define M_DIM 16384
#define N_DIM 2048
#define K_DIM 2048
#define NELEM (M_DIM * K_DIM)      // 33554432
#define NGROUPS (NELEM / 4)        // 8388608
#define WELEM (N_DIM * K_DIM)      // 4194304
#define PRUNE_BLOCKS 8192

__device__ __forceinline__ u16 f2bf(float f) {
    union { float f; uint32_t u; } c; c.f = f;
    uint32_t r = c.u + 0x7FFFu + ((c.u >> 16) & 1u);   // round-to-nearest-even
    return (u16)(r >> 16);
}

// -------------------------------------------------------------------------
// Kernel 1: 2:4 prune + bf16 convert; per-block float4 partial sums
// (NO atomics — round-1 theory: 32768 same-line device atomics serialized
//  the kernel tail. Partials + finalize kernel instead.)
// -------------------------------------------------------------------------
__global__ __launch_bounds__(256) void prune_kernel(const float* __restrict__ x,
                                                    u16* __restrict__ xsp,
                                                    float4* __restrict__ partials) {
    float sx = 0.f, sxx = 0.f, sp = 0.f, spp = 0.f;
    const int stride = gridDim.x * 256;
    for (int g = blockIdx.x * 256 + threadIdx.x; g < NGROUPS; g += stride) {
        float4 v = ((const float4*)x)[g];
        float a0 = v.x, a1 = v.y, a2 = v.z, a3 = v.w;
        float b0 = fabsf(a0), b1 = fabsf(a1), b2 = fabsf(a2), b3 = fabsf(a3);
        // rank_i = #{j : |a_j|>|a_i| or (|a_j|==|a_i| and j<i)} -> keep if rank<2
        int r0 = (b1 > b0) + (b2 > b0) + (b3 > b0);
        int r1 = (b0 >= b1) + (b2 > b1) + (b3 > b1);
        int r2 = (b0 >= b2) + (b1 >= b2) + (b3 > b2);
        int r3 = (b0 >= b3) + (b1 >= b3) + (b2 >= b3);
        float k0 = (r0 < 2) ? a0 : 0.f;
        float k1 = (r1 < 2) ? a1 : 0.f;
        float k2 = (r2 < 2) ? a2 : 0.f;
        float k3 = (r3 < 2) ? a3 : 0.f;
        sx  += a0 + a1 + a2 + a3;
        sxx += a0*a0 + a1*a1 + a2*a2 + a3*a3;
        sp  += k0 + k1 + k2 + k3;
        spp += k0*k0 + k1*k1 + k2*k2 + k3*k3;
        u16x4 o;
        o.x = f2bf(k0); o.y = f2bf(k1); o.z = f2bf(k2); o.w = f2bf(k3);
        ((u16x4*)xsp)[g] = o;
    }
    // wave reduce (64 lanes)
    for (int off = 32; off > 0; off >>= 1) {
        sx  += __shfl_down(sx,  off, 64);
        sxx += __shfl_down(sxx, off, 64);
        sp  += __shfl_down(sp,  off, 64);
        spp += __shfl_down(spp, off, 64);
    }
    __shared__ float red[4][4];
    int wid = threadIdx.x >> 6, lane = threadIdx.x & 63;
    if (lane == 0) { red[wid][0] = sx; red[wid][1] = sxx; red[wid][2] = sp; red[wid][3] = spp; }
    __syncthreads();
    if (threadIdx.x == 0) {
        float4 t;
        t.x = red[0][0] + red[1][0] + red[2][0] + red[3][0];
        t.y = red[0][1] + red[1][1] + red[2][1] + red[3][1];
        t.z = red[0][2] + red[1][2] + red[2][2] + red[3][2];
        t.w = red[0][3] + red[1][3] + red[2][3] + red[3][3];
        partials[blockIdx.x] = t;
    }
}

// -------------------------------------------------------------------------
// Kernel 1b: reduce partials, compute v = sqrt(var(x)/max(var(x_sp),1e-9))
// -------------------------------------------------------------------------
__global__ __launch_bounds__(256) void finalize_kernel(const float4* __restrict__ partials,
                                                       float* __restrict__ vout) {
    float sx = 0.f, sxx = 0.f, sp = 0.f, spp = 0.f;
    for (int i = threadIdx.x; i < PRUNE_BLOCKS; i += 256) {
        float4 t = partials[i];
        sx += t.x; sxx += t.y; sp += t.z; spp += t.w;
    }
    for (int off = 32; off > 0; off >>= 1) {
        sx  += __shfl_down(sx,  off, 64);
        sxx += __shfl_down(sxx, off, 64);
        sp  += __shfl_down(sp,  off, 64);
        spp += __shfl_down(spp, off, 64);
    }
    __shared__ float red[4][4];
    int wid = threadIdx.x >> 6, lane = threadIdx.x & 63;
    if (lane == 0) { red[wid][0] = sx; red[wid][1] = sxx; red[wid][2] = sp; red[wid][3] = spp; }
    __syncthreads();
    if (threadIdx.x == 0) {
        float tsx  = red[0][0] + red[1][0] + red[2][0] + red[3][0];
        float tsxx = red[0][1] + red[1][1] + red[2][1] + red[3][1];
        float tsp  = red[0][2] + red[1][2] + red[2][2] + red[3][2];
        float tspp = red[0][3] + red[1][3] + red[2][3] + red[3][3];
        const float n = (float)NELEM;
        float varx = (tsxx - tsx * tsx / n) / (n - 1.f);
        float varp = (tspp - tsp * tsp / n) / (n - 1.f);
        varp = fmaxf(varp, 1e-9f);
        vout[0] = sqrtf(varx / varp);
    }
}

// -------------------------------------------------------------------------
// Kernel 2: weight fp32 -> bf16
// -------------------------------------------------------------------------
__global__ __launch_bounds__(256) void wconv_kernel(const float* __restrict__ w,
                                                    u16* __restrict__ wb) {
    int i = blockIdx.x * 256 + threadIdx.x;   // over WELEM/4 exactly
    float4 v = ((const float4*)w)[i];
    u16x4 o;
    o.x = f2bf(v.x); o.y = f2bf(v.y); o.z = f2bf(v.z); o.w = f2bf(v.w);
    ((u16x4*)wb)[i] = o;
}

// -------------------------------------------------------------------------
// Kernel 3: bf16 MFMA GEMM (m97 structure), unchanged except v is
// precomputed by finalize_kernel and loaded as a single float.
// -------------------------------------------------------------------------
#define GLD16(g, l) \
    __builtin_amdgcn_global_load_lds((__attribute__((address_space(1))) void*)(g), \
                                     (__attribute__((address_space(3))) void*)(l), 16, 0, 0)

__global__ __launch_bounds__(256) void gemm_kernel(const u16* __restrict__ A,
                                                   const u16* __restrict__ B,
                                                   const float* __restrict__ vscale,
                                                   float* __restrict__ out) {
    __shared__ __align__(16) u16 As[128 * 32];   // 8 KiB, lane-linear (no pad: global_load_lds)
    __shared__ __align__(16) u16 Bs[128 * 32];   // 8 KiB

    const int tid  = threadIdx.x;
    const int lane = tid & 63;
    const int wid  = tid >> 6;
    const int wm   = (wid >> 1) * 64;   // wave tile origin in M within block
    const int wn   = (wid & 1) * 64;    // wave tile origin in N within block
    const int l15  = lane & 15;
    const int quad = lane >> 4;
    const int m0 = blockIdx.y * 128;
    const int n0 = blockIdx.x * 128;

    const int idx0 = tid;
    const int idx1 = tid + 256;
    const int rA0 = idx0 >> 2, sA0 = (idx0 & 3) * 8;
    const int rA1 = idx1 >> 2, sA1 = (idx1 & 3) * 8;
    const u16* gA0 = A + (size_t)(m0 + rA0) * K_DIM + sA0;
    const u16* gA1 = A + (size_t)(m0 + rA1) * K_DIM + sA1;
    const u16* gB0 = B + (size_t)(n0 + rA0) * K_DIM + sA0;
    const u16* gB1 = B + (size_t)(n0 + rA1) * K_DIM + sA1;

    f32x4 acc[4][4] = {};

    for (int kt = 0; kt < K_DIM / 32; ++kt) {
        GLD16(gA0, &As[idx0 * 8]);
        GLD16(gA1, &As[idx1 * 8]);
        GLD16(gB0, &Bs[idx0 * 8]);
        GLD16(gB1, &Bs[idx1 * 8]);
        gA0 += 32; gA1 += 32; gB0 += 32; gB1 += 32;
        __syncthreads();

        const bf16x8* Ap = (const bf16x8*)As;
        const bf16x8* Bp = (const bf16x8*)Bs;
        bf16x8 aF[4], bF[4];
#pragma unroll
        for (int i = 0; i < 4; ++i)
            aF[i] = Ap[(wm + i * 16 + l15) * 4 + quad];   // A[m=l15][k=quad*8+j]
#pragma unroll
        for (int j = 0; j < 4; ++j)
            bF[j] = Bp[(wn + j * 16 + l15) * 4 + quad];   // B[n=l15][k=quad*8+j]
#pragma unroll
        for (int i = 0; i < 4; ++i)
#pragma unroll
            for (int j = 0; j < 4; ++j)
                acc[i][j] = __builtin_amdgcn_mfma_f32_16x16x32_bf16(aF[i], bF[j], acc[i][j], 0, 0, 0);
        __syncthreads();
    }

    const float v = vscale[0];

    // C/D layout: col = lane&15, row = quad*4 + reg
    float* op = out + (size_t)(m0 + wm) * N_DIM + n0 + wn;
#pragma unroll
    for (int i = 0; i < 4; ++i)
#pragma unroll
        for (int j = 0; j < 4; ++j)
#pragma unroll
            for (int r = 0; r < 4; ++r)
                op[(size_t)(i * 16 + quad * 4 + r) * N_DIM + j * 16 + l15] = acc[i][j][r] * v;
}

extern "C" void kernel_launch(void* const* d_in, const int* in_sizes, int n_in,
                              void* d_out, int out_size, void* d_ws, size_t ws_size,
                              hipStream_t stream) {
    const float* x = (const float*)d_in[0];
    const float* w = (const float*)d_in[1];
    float* out = (float*)d_out;

    u16* xsp      = (u16*)d_ws;                   // 64 MiB: bf16 x_sp [16384][2048]
    u16* wb       = xsp + NELEM;                  // 8 MiB:  bf16 W    [2048][2048]
    float4* parts = (float4*)(wb + WELEM);        // 128 KiB: per-block {sx,sxx,sp,spp}
    float* vbuf   = (float*)(parts + PRUNE_BLOCKS); // 4 B: v

    prune_kernel<<<PRUNE_BLOCKS, 256, 0, stream>>>(x, xsp, parts);
    finalize_kernel<<<1, 256, 0, stream>>>(parts, vbuf);
    wconv_kernel<<<WELEM / 4 / 256, 256, 0, stream>>>(w, wb);
    dim3 grid(N_DIM / 128, M_DIM / 128);
    gemm_kernel<<<grid, 256, 0, stream>>>(xsp, wb, vbuf, out);
}

// Round 3
// 397.418 us; speedup vs baseline: 1.1460x; 1.0076x over previous
//
#include <hip/hip_runtime.h>
#include <stdint.h>

typedef unsigned short u16;
typedef __attribute__((ext_vector_type(4))) unsigned short u16x4;
typedef __attribute__((ext_vector_type(4))) float f32x4;
typedef __attribute__((ext_vector_type(8))) __bf16 bf16x8;

#define M_DIM 16384
#define N_DIM 2048
#define K_DIM 2048
#define NELEM (M_DIM * K_DIM)      // 33554432
#define NGROUPS (NELEM / 4)        // 8388608
#define WELEM (N_DIM * K_DIM)      // 4194304
#define PRUNE_BLOCKS 2048
#define PRUNE_ITERS (NGROUPS / (PRUNE_BLOCKS * 256))   // 16, exact

__device__ __forceinline__ u16 f2bf(float f) {
    union { float f; uint32_t u; } c; c.f = f;
    uint32_t r = c.u + 0x7FFFu + ((c.u >> 16) & 1u);   // round-to-nearest-even
    return (u16)(r >> 16);
}

// -------------------------------------------------------------------------
// Kernel 1: 2:4 prune + bf16 convert; per-block float4 partials.
// R3: 2048 blocks x exactly 16 iters, unroll-4 for SW pipelining (H1 test).
// -------------------------------------------------------------------------
__global__ __launch_bounds__(256) void prune_kernel(const float* __restrict__ x,
                                                    u16* __restrict__ xsp,
                                                    float4* __restrict__ partials) {
    float sx = 0.f, sxx = 0.f, sp = 0.f, spp = 0.f;
    int g = blockIdx.x * 256 + threadIdx.x;
    const int stride = PRUNE_BLOCKS * 256;
#pragma unroll 4
    for (int it = 0; it < PRUNE_ITERS; ++it, g += stride) {
        float4 v = ((const float4*)x)[g];
        float a0 = v.x, a1 = v.y, a2 = v.z, a3 = v.w;
        float b0 = fabsf(a0), b1 = fabsf(a1), b2 = fabsf(a2), b3 = fabsf(a3);
        // rank_i = #{j : |a_j|>|a_i| or (|a_j|==|a_i| and j<i)} -> keep if rank<2
        int r0 = (b1 > b0) + (b2 > b0) + (b3 > b0);
        int r1 = (b0 >= b1) + (b2 > b1) + (b3 > b1);
        int r2 = (b0 >= b2) + (b1 >= b2) + (b3 > b2);
        int r3 = (b0 >= b3) + (b1 >= b3) + (b2 >= b3);
        float k0 = (r0 < 2) ? a0 : 0.f;
        float k1 = (r1 < 2) ? a1 : 0.f;
        float k2 = (r2 < 2) ? a2 : 0.f;
        float k3 = (r3 < 2) ? a3 : 0.f;
        sx  += a0 + a1 + a2 + a3;
        sxx += a0*a0 + a1*a1 + a2*a2 + a3*a3;
        sp  += k0 + k1 + k2 + k3;
        spp += k0*k0 + k1*k1 + k2*k2 + k3*k3;
        u16x4 o;
        o.x = f2bf(k0); o.y = f2bf(k1); o.z = f2bf(k2); o.w = f2bf(k3);
        ((u16x4*)xsp)[g] = o;
    }
    // wave reduce (64 lanes)
    for (int off = 32; off > 0; off >>= 1) {
        sx  += __shfl_down(sx,  off, 64);
        sxx += __shfl_down(sxx, off, 64);
        sp  += __shfl_down(sp,  off, 64);
        spp += __shfl_down(spp, off, 64);
    }
    __shared__ float red[4][4];
    int wid = threadIdx.x >> 6, lane = threadIdx.x & 63;
    if (lane == 0) { red[wid][0] = sx; red[wid][1] = sxx; red[wid][2] = sp; red[wid][3] = spp; }
    __syncthreads();
    if (threadIdx.x == 0) {
        float4 t;
        t.x = red[0][0] + red[1][0] + red[2][0] + red[3][0];
        t.y = red[0][1] + red[1][1] + red[2][1] + red[3][1];
        t.z = red[0][2] + red[1][2] + red[2][2] + red[3][2];
        t.w = red[0][3] + red[1][3] + red[2][3] + red[3][3];
        partials[blockIdx.x] = t;
    }
}

// -------------------------------------------------------------------------
// Kernel 1b: reduce partials, compute v = sqrt(var(x)/max(var(x_sp),1e-9))
// -------------------------------------------------------------------------
__global__ __launch_bounds__(256) void finalize_kernel(const float4* __restrict__ partials,
                                                       float* __restrict__ vout) {
    float sx = 0.f, sxx = 0.f, sp = 0.f, spp = 0.f;
#pragma unroll
    for (int i = 0; i < PRUNE_BLOCKS / 256; ++i) {
        float4 t = partials[i * 256 + threadIdx.x];
        sx += t.x; sxx += t.y; sp += t.z; spp += t.w;
    }
    for (int off = 32; off > 0; off >>= 1) {
        sx  += __shfl_down(sx,  off, 64);
        sxx += __shfl_down(sxx, off, 64);
        sp  += __shfl_down(sp,  off, 64);
        spp += __shfl_down(spp, off, 64);
    }
    __shared__ float red[4][4];
    int wid = threadIdx.x >> 6, lane = threadIdx.x & 63;
    if (lane == 0) { red[wid][0] = sx; red[wid][1] = sxx; red[wid][2] = sp; red[wid][3] = spp; }
    __syncthreads();
    if (threadIdx.x == 0) {
        float tsx  = red[0][0] + red[1][0] + red[2][0] + red[3][0];
        float tsxx = red[0][1] + red[1][1] + red[2][1] + red[3][1];
        float tsp  = red[0][2] + red[1][2] + red[2][2] + red[3][2];
        float tspp = red[0][3] + red[1][3] + red[2][3] + red[3][3];
        const float n = (float)NELEM;
        float varx = (tsxx - tsx * tsx / n) / (n - 1.f);
        float varp = (tspp - tsp * tsp / n) / (n - 1.f);
        varp = fmaxf(varp, 1e-9f);
        vout[0] = sqrtf(varx / varp);
    }
}

// -------------------------------------------------------------------------
// Kernel 2: weight fp32 -> bf16
// -------------------------------------------------------------------------
__global__ __launch_bounds__(256) void wconv_kernel(const float* __restrict__ w,
                                                    u16* __restrict__ wb) {
    int i = blockIdx.x * 256 + threadIdx.x;   // over WELEM/4 exactly
    float4 v = ((const float4*)w)[i];
    u16x4 o;
    o.x = f2bf(v.x); o.y = f2bf(v.y); o.z = f2bf(v.z); o.w = f2bf(v.w);
    ((u16x4*)wb)[i] = o;
}

// -------------------------------------------------------------------------
// Kernel 3: bf16 MFMA GEMM (m97 structure) + R3 XCD swizzle:
// 1D grid 2048; b&7 = XCD, each XCD owns 16 contiguous m-rows so all 16
// n-blocks sharing an A-tile land in one XCD's L2.
// -------------------------------------------------------------------------
#define GLD16(g, l) \
    __builtin_amdgcn_global_load_lds((__attribute__((address_space(1))) void*)(g), \
                                     (__attribute__((address_space(3))) void*)(l), 16, 0, 0)

__global__ __launch_bounds__(256) void gemm_kernel(const u16* __restrict__ A,
                                                   const u16* __restrict__ B,
                                                   const float* __restrict__ vscale,
                                                   float* __restrict__ out) {
    __shared__ __align__(16) u16 As[128 * 32];   // 8 KiB, lane-linear (no pad: global_load_lds)
    __shared__ __align__(16) u16 Bs[128 * 32];   // 8 KiB

    const int tid  = threadIdx.x;
    const int lane = tid & 63;
    const int wid  = tid >> 6;
    const int wm   = (wid >> 1) * 64;
    const int wn   = (wid & 1) * 64;
    const int l15  = lane & 15;
    const int quad = lane >> 4;

    // XCD-aware swizzle: b -> (mrow, ncol); bijective over 8*16 x 16 = 2048
    const int b    = blockIdx.x;
    const int xcd  = b & 7;
    const int s    = b >> 3;             // 0..255
    const int mrow = xcd * 16 + (s >> 4);
    const int ncol = s & 15;
    const int m0 = mrow * 128;
    const int n0 = ncol * 128;

    const int idx0 = tid;
    const int idx1 = tid + 256;
    const int rA0 = idx0 >> 2, sA0 = (idx0 & 3) * 8;
    const int rA1 = idx1 >> 2, sA1 = (idx1 & 3) * 8;
    const u16* gA0 = A + (size_t)(m0 + rA0) * K_DIM + sA0;
    const u16* gA1 = A + (size_t)(m0 + rA1) * K_DIM + sA1;
    const u16* gB0 = B + (size_t)(n0 + rA0) * K_DIM + sA0;
    const u16* gB1 = B + (size_t)(n0 + rA1) * K_DIM + sA1;

    f32x4 acc[4][4] = {};

    for (int kt = 0; kt < K_DIM / 32; ++kt) {
        GLD16(gA0, &As[idx0 * 8]);
        GLD16(gA1, &As[idx1 * 8]);
        GLD16(gB0, &Bs[idx0 * 8]);
        GLD16(gB1, &Bs[idx1 * 8]);
        gA0 += 32; gA1 += 32; gB0 += 32; gB1 += 32;
        __syncthreads();

        const bf16x8* Ap = (const bf16x8*)As;
        const bf16x8* Bp = (const bf16x8*)Bs;
        bf16x8 aF[4], bF[4];
#pragma unroll
        for (int i = 0; i < 4; ++i)
            aF[i] = Ap[(wm + i * 16 + l15) * 4 + quad];   // A[m=l15][k=quad*8+j]
#pragma unroll
        for (int j = 0; j < 4; ++j)
            bF[j] = Bp[(wn + j * 16 + l15) * 4 + quad];   // B[n=l15][k=quad*8+j]
#pragma unroll
        for (int i = 0; i < 4; ++i)
#pragma unroll
            for (int j = 0; j < 4; ++j)
                acc[i][j] = __builtin_amdgcn_mfma_f32_16x16x32_bf16(aF[i], bF[j], acc[i][j], 0, 0, 0);
        __syncthreads();
    }

    const float v = vscale[0];

    // C/D layout: col = lane&15, row = quad*4 + reg
    float* op = out + (size_t)(m0 + wm) * N_DIM + n0 + wn;
#pragma unroll
    for (int i = 0; i < 4; ++i)
#pragma unroll
        for (int j = 0; j < 4; ++j)
#pragma unroll
            for (int r = 0; r < 4; ++r)
                op[(size_t)(i * 16 + quad * 4 + r) * N_DIM + j * 16 + l15] = acc[i][j][r] * v;
}

extern "C" void kernel_launch(void* const* d_in, const int* in_sizes, int n_in,
                              void* d_out, int out_size, void* d_ws, size_t ws_size,
                              hipStream_t stream) {
    const float* x = (const float*)d_in[0];
    const float* w = (const float*)d_in[1];
    float* out = (float*)d_out;

    u16* xsp      = (u16*)d_ws;                     // 64 MiB: bf16 x_sp [16384][2048]
    u16* wb       = xsp + NELEM;                    // 8 MiB:  bf16 W    [2048][2048]
    float4* parts = (float4*)(wb + WELEM);          // 32 KiB: per-block {sx,sxx,sp,spp}
    float* vbuf   = (float*)(parts + PRUNE_BLOCKS); // 4 B: v

    prune_kernel<<<PRUNE_BLOCKS, 256, 0, stream>>>(x, xsp, parts);
    finalize_kernel<<<1, 256, 0, stream>>>(parts, vbuf);
    wconv_kernel<<<WELEM / 4 / 256, 256, 0, stream>>>(w, wb);
    gemm_kernel<<<2048, 256, 0, stream>>>(xsp, wb, vbuf, out);
}